// Round 1
// baseline (294.693 us; speedup 1.0000x reference)
//
#include <hip/hip_runtime.h>
#include <hip/hip_bf16.h>

// Problem constants
#define BATCH 16
#define INCH 16
#define HH 64
#define WW 64
#define HO 62
#define WO 62
#define OUTCH 128
#define KD 9          // 3x3 kernel positions
#define NTRI 45       // upper-triangle pairs of 9
#define KFULL 1296    // 16*81

// Upper-triangle pair enumeration (a<=b)
__device__ constexpr int TRI_A[NTRI] = {
  0,0,0,0,0,0,0,0,0,
  1,1,1,1,1,1,1,1,
  2,2,2,2,2,2,2,
  3,3,3,3,3,3,
  4,4,4,4,4,
  5,5,5,5,
  6,6,6,
  7,7,
  8};
__device__ constexpr int TRI_B[NTRI] = {
  0,1,2,3,4,5,6,7,8,
  1,2,3,4,5,6,7,8,
  2,3,4,5,6,7,8,
  3,4,5,6,7,8,
  4,5,6,7,8,
  5,6,7,8,
  6,7,8,
  7,8,
  8};

// Prep: symmetrize W into Wt[c][t][o] (o contiguous for coalesced staging)
__global__ void prep_wsym(const float* __restrict__ W, float* __restrict__ Wt) {
  int idx = blockIdx.x * 256 + threadIdx.x;
  if (idx >= INCH * NTRI * OUTCH) return;
  int o = idx & 127;
  int t = (idx >> 7) % NTRI;
  int c = idx / (OUTCH * NTRI);
  int a = TRI_A[t], b = TRI_B[t];
  float v = W[o * KFULL + c * 81 + a * 9 + b];
  if (a != b) v += W[o * KFULL + c * 81 + b * 9 + a];
  Wt[(c * NTRI + t) * OUTCH + o] = v;
}

// Main: one block per (batch, output-row). 256 threads.
// thread -> og = tid>>4 (8 outputs: og*8..og*8+7), pg = tid&15
// positions x = pg + 16*pp, pp=0..3  (x in 0..63; x>=62 masked at write)
__global__ __launch_bounds__(256, 4) void conv2o_main(
    const float* __restrict__ X, const float* __restrict__ Wraw,
    const float* __restrict__ Wt, float* __restrict__ Out, int use_ws) {
  __shared__ float xs[INCH][3][66];
  __shared__ float wl[NTRI][OUTCH];

  int blk = blockIdx.x;
  int b = blk / HO;
  int y = blk % HO;
  int tid = threadIdx.x;

  // Stage 3 input rows x 16 channels (cols 0..65; clamp to 63 -> masked later)
  for (int i = tid; i < INCH * 3 * 66; i += 256) {
    int c = i / (3 * 66);
    int rem = i % (3 * 66);
    int r = rem / 66, col = rem % 66;
    int colg = col < WW ? col : WW - 1;
    xs[c][r][col] = X[((b * INCH + c) * HH + (y + r)) * WW + colg];
  }

  int og = tid >> 4;
  int pg = tid & 15;
  int o0 = og * 8;

  float acc[4][8];
#pragma unroll
  for (int p = 0; p < 4; ++p)
#pragma unroll
    for (int q = 0; q < 8; ++q) acc[p][q] = 0.f;

  for (int c = 0; c < INCH; ++c) {
    __syncthreads();
    if (use_ws) {
      const float4* src = (const float4*)(Wt + c * NTRI * OUTCH);
      float4* dst = (float4*)&wl[0][0];
      for (int i = tid; i < NTRI * OUTCH / 4; i += 256) dst[i] = src[i];
    } else {
      for (int i = tid; i < NTRI * OUTCH; i += 256) {
        int t = i >> 7, o = i & 127;
        int a = TRI_A[t], bb = TRI_B[t];
        float v = Wraw[o * KFULL + c * 81 + a * 9 + bb];
        if (a != bb) v += Wraw[o * KFULL + c * 81 + bb * 9 + a];
        wl[t][o] = v;
      }
    }
    __syncthreads();

    // patch values for my 4 positions into registers
    float pr[4][9];
#pragma unroll
    for (int pp = 0; pp < 4; ++pp) {
      int xcol = pg + 16 * pp;
#pragma unroll
      for (int iy = 0; iy < 3; ++iy)
#pragma unroll
        for (int jx = 0; jx < 3; ++jx)
          pr[pp][iy * 3 + jx] = xs[c][iy][xcol + jx];
    }

#pragma unroll
    for (int t = 0; t < NTRI; ++t) {
      const int a = TRI_A[t], bb = TRI_B[t];
      float4 w0 = *(const float4*)&wl[t][o0];
      float4 w1 = *(const float4*)&wl[t][o0 + 4];
#pragma unroll
      for (int pp = 0; pp < 4; ++pp) {
        float prod = pr[pp][a] * pr[pp][bb];
        acc[pp][0] += w0.x * prod;
        acc[pp][1] += w0.y * prod;
        acc[pp][2] += w0.z * prod;
        acc[pp][3] += w0.w * prod;
        acc[pp][4] += w1.x * prod;
        acc[pp][5] += w1.y * prod;
        acc[pp][6] += w1.z * prod;
        acc[pp][7] += w1.w * prod;
      }
    }
  }

  // Write: for fixed (pp,q), 16 lanes write 16 consecutive l
  int lbase = y * WO;
#pragma unroll
  for (int pp = 0; pp < 4; ++pp) {
    int xcol = pg + 16 * pp;
    if (xcol < WO) {
#pragma unroll
      for (int q = 0; q < 8; ++q) {
        int o = o0 + q;
        Out[(b * OUTCH + o) * (HO * WO) + lbase + xcol] = acc[pp][q];
      }
    }
  }
}

extern "C" void kernel_launch(void* const* d_in, const int* in_sizes, int n_in,
                              void* d_out, int out_size, void* d_ws, size_t ws_size,
                              hipStream_t stream) {
  const float* X = (const float*)d_in[0];
  const float* W = (const float*)d_in[1];
  float* Out = (float*)d_out;

  size_t wsym_bytes = (size_t)INCH * NTRI * OUTCH * sizeof(float);
  int use_ws = (ws_size >= wsym_bytes) ? 1 : 0;
  float* Wt = (float*)d_ws;

  if (use_ws) {
    int total = INCH * NTRI * OUTCH;
    prep_wsym<<<(total + 255) / 256, 256, 0, stream>>>(W, Wt);
  }
  conv2o_main<<<BATCH * HO, 256, 0, stream>>>(X, W, Wt, Out, use_ws);
}

// Round 3
// 113.357 us; speedup vs baseline: 2.5997x; 2.5997x over previous
//
#include <hip/hip_runtime.h>
#include <hip/hip_bf16.h>

#define BATCH 16
#define INCH 16
#define HH 64
#define WW 64
#define HO 62
#define WO 62
#define LTOT (HO * WO)      // 3844
#define OUTCH 128
#define KFULL 1296
#define NTRI 45
#define NSC 8               // super-chunks, 2 channels each
#define KPC 96              // padded K per super-chunk (2 * 48)
#define TILE_N 124          // 2 output rows per block
#define NTILES 31           // 31 * 124 == 3844
#define FROW 52             // dwords per LDS row (208 B, bank-optimal pad)

typedef short bf16x8 __attribute__((ext_vector_type(8)));
typedef float f32x4 __attribute__((ext_vector_type(4)));

__device__ constexpr int TRI_A[NTRI] = {
  0,0,0,0,0,0,0,0,0, 1,1,1,1,1,1,1,1, 2,2,2,2,2,2,2,
  3,3,3,3,3,3, 4,4,4,4,4, 5,5,5,5, 6,6,6, 7,7, 8};
__device__ constexpr int TRI_B[NTRI] = {
  0,1,2,3,4,5,6,7,8, 1,2,3,4,5,6,7,8, 2,3,4,5,6,7,8,
  3,4,5,6,7,8, 4,5,6,7,8, 5,6,7,8, 6,7,8, 7,8, 8};

__device__ inline unsigned short f2bf(float x) {  // RNE
  unsigned int u = __float_as_uint(x);
  unsigned int r = ((u >> 16) & 1u) + 0x7FFFu;
  return (unsigned short)((u + r) >> 16);
}
__device__ inline unsigned int pack2(float a, float b) {
  return (unsigned int)f2bf(a) | ((unsigned int)f2bf(b) << 16);
}

// symmetrized W element for fallback path: kl in [0,96)
__device__ inline float wsym_at(const float* __restrict__ W, int sc, int o, int kl) {
  int half = kl >= 48 ? 1 : 0;
  int t = kl - 48 * half;
  if (t >= NTRI) return 0.f;
  int a = TRI_A[t], b = TRI_B[t];
  int c = sc * 2 + half;
  float v = W[o * KFULL + c * 81 + a * 9 + b];
  if (a != b) v += W[o * KFULL + c * 81 + b * 9 + a];
  return v;
}

// Prep: Wp[sc][o][kl] bf16, kl = half*48 + t (t>=45 zero-padded)
__global__ void prep_w(const float* __restrict__ W, unsigned short* __restrict__ Wp) {
  int idx = blockIdx.x * 256 + threadIdx.x;
  if (idx >= NSC * OUTCH * KPC) return;
  int kl = idx % KPC;
  int o = (idx / KPC) % OUTCH;
  int sc = idx / (KPC * OUTCH);
  Wp[idx] = f2bf(wsym_at(W, sc, o, kl));
}

__global__ __launch_bounds__(256, 2) void conv2o_mfma(
    const float* __restrict__ X, const float* __restrict__ Wraw,
    const unsigned int* __restrict__ Wp, float* __restrict__ Out, int use_ws) {
  __shared__ unsigned int Wl[OUTCH * FROW];  // A: [o][k] bf16, 208B rows
  __shared__ unsigned int Fl[128 * FROW];    // B^T: [pos][k] bf16
  __shared__ float xsb[2][2][4][64];         // dbuf x 2ch x 4 rows x 64 cols

  const int tid = threadIdx.x;
  const int blk = blockIdx.x;
  const int b = blk / NTILES;
  const int tile = blk % NTILES;
  const int y0 = tile * 2;
  const int l0 = tile * TILE_N;

  const int lane = tid & 63;
  const int wave = tid >> 6;
  const int mbase = (wave >> 1) * 64;  // o range of this wave
  const int nbase = (wave & 1) * 64;   // pos range of this wave
  const int lr = lane & 15;            // frag row/col low index
  const int lh = lane >> 4;            // frag k-group / acc row group

  // ---- prologue: stage xs(0), prefetch W(0) ----
  if (tid < 128) {
    int ch = tid >> 6, r = (tid >> 4) & 3, seg = tid & 15;
    const float4 v = *(const float4*)&X[(((b * INCH) + ch) * HH + (y0 + r)) * WW + seg * 4];
    *(float4*)&xsb[0][ch][r][seg * 4] = v;
  }
  uint4 wpf[6];
  if (use_ws) {
    const uint4* ws = (const uint4*)Wp;  // 1536 uint4 per sc
#pragma unroll
    for (int i = 0; i < 6; ++i) wpf[i] = ws[tid + i * 256];
  }
  __syncthreads();

  f32x4 acc[4][4];
#pragma unroll
  for (int mf = 0; mf < 4; ++mf)
#pragma unroll
    for (int nf = 0; nf < 4; ++nf) acc[mf][nf] = (f32x4){0.f, 0.f, 0.f, 0.f};

  const int q = tid & 127;
  const int half = tid >> 7;
  const int qrow = q / 62;             // 0/1 valid when q<124
  const int qcol = q - qrow * 62;

  for (int sc = 0; sc < NSC; ++sc) {
    // ---------- phase A: stage W(sc), compute F(sc), prefetch sc+1 ----------
    if (use_ws) {
#pragma unroll
      for (int i = 0; i < 6; ++i) {
        int n = tid + i * 256;
        int o = n / 12, d4 = n % 12;
        *(uint4*)&Wl[o * FROW + d4 * 4] = wpf[i];
      }
    } else {
      for (int i = tid; i < OUTCH * 48; i += 256) {
        int o = i / 48, dd = i % 48;
        Wl[o * FROW + dd] =
            pack2(wsym_at(Wraw, sc, o, 2 * dd), wsym_at(Wraw, sc, o, 2 * dd + 1));
      }
    }
    // issue prefetches for sc+1 (land during MFMA phase)
    if (use_ws && sc + 1 < NSC) {
      const uint4* ws = (const uint4*)Wp + (size_t)(sc + 1) * 1536;
#pragma unroll
      for (int i = 0; i < 6; ++i) wpf[i] = ws[tid + i * 256];
    }
    float4 xpf;
    const int havex = (sc + 1 < NSC) && (tid < 128);
    if (havex) {
      int ch = tid >> 6, r = (tid >> 4) & 3, seg = tid & 15;
      xpf = *(const float4*)&X[(((b * INCH) + ((sc + 1) * 2 + ch)) * HH + (y0 + r)) * WW + seg * 4];
    }
    // F-compute: 2 threads per position (half = channel within sc)
    {
      unsigned int d[24];
      if (q < TILE_N) {
        float p[9];
#pragma unroll
        for (int di = 0; di < 3; ++di)
#pragma unroll
          for (int dj = 0; dj < 3; ++dj)
            p[di * 3 + dj] = xsb[sc & 1][half][qrow + di][qcol + dj];
#pragma unroll
        for (int j = 0; j < 24; ++j) {
          float lo = (2 * j < NTRI) ? p[TRI_A[2 * j]] * p[TRI_B[2 * j]] : 0.f;
          float hi = (2 * j + 1 < NTRI) ? p[TRI_A[2 * j + 1]] * p[TRI_B[2 * j + 1]] : 0.f;
          d[j] = pack2(lo, hi);
        }
      } else {
#pragma unroll
        for (int j = 0; j < 24; ++j) d[j] = 0u;
      }
      const unsigned base = q * FROW + half * 24;
#pragma unroll
      for (int j = 0; j < 6; ++j) {
        uint4 v = make_uint4(d[4 * j], d[4 * j + 1], d[4 * j + 2], d[4 * j + 3]);
        *(uint4*)&Fl[base + j * 4] = v;
      }
    }
    // write xs(sc+1) into the other buffer
    if (havex) {
      int ch = tid >> 6, r = (tid >> 4) & 3, seg = tid & 15;
      *(float4*)&xsb[(sc + 1) & 1][ch][r][seg * 4] = xpf;
    }
    __syncthreads();

    // ---------- phase B: MFMA over 3 k-chunks ----------
#pragma unroll
    for (int kc = 0; kc < 3; ++kc) {
      const int koff = kc * 16 + lh * 4;  // dword offset within a row
      bf16x8 af[4], bfr[4];
#pragma unroll
      for (int mf = 0; mf < 4; ++mf)
        af[mf] = *(const bf16x8*)&Wl[(mbase + mf * 16 + lr) * FROW + koff];
#pragma unroll
      for (int nf = 0; nf < 4; ++nf)
        bfr[nf] = *(const bf16x8*)&Fl[(nbase + nf * 16 + lr) * FROW + koff];
#pragma unroll
      for (int mf = 0; mf < 4; ++mf)
#pragma unroll
        for (int nf = 0; nf < 4; ++nf)
          acc[mf][nf] =
              __builtin_amdgcn_mfma_f32_16x16x32_bf16(af[mf], bfr[nf], acc[mf][nf], 0, 0, 0);
    }
    __syncthreads();
  }

  // ---------- epilogue: D frag col = pos (lane&15), row = o (lh*4 + r) ----------
#pragma unroll
  for (int nf = 0; nf < 4; ++nf) {
    const int pos = nbase + nf * 16 + lr;
    if (pos < TILE_N) {
      const int l = l0 + pos;
#pragma unroll
      for (int mf = 0; mf < 4; ++mf) {
        const int o = mbase + mf * 16 + lh * 4;
        float* outp = &Out[((size_t)(b * OUTCH + o)) * LTOT + l];
#pragma unroll
        for (int r = 0; r < 4; ++r) outp[(size_t)r * LTOT] = acc[mf][nf][r];
      }
    }
  }
}

extern "C" void kernel_launch(void* const* d_in, const int* in_sizes, int n_in,
                              void* d_out, int out_size, void* d_ws, size_t ws_size,
                              hipStream_t stream) {
  const float* X = (const float*)d_in[0];
  const float* W = (const float*)d_in[1];
  float* Out = (float*)d_out;

  const size_t wp_bytes = (size_t)NSC * OUTCH * KPC * sizeof(unsigned short);
  const int use_ws = (ws_size >= wp_bytes) ? 1 : 0;

  if (use_ws) {
    int total = NSC * OUTCH * KPC;
    prep_w<<<(total + 255) / 256, 256, 0, stream>>>(W, (unsigned short*)d_ws);
  }
  conv2o_mfma<<<BATCH * NTILES, 256, 0, stream>>>(X, W, (const unsigned int*)d_ws, Out, use_ws);
}

// Round 7
// 86.736 us; speedup vs baseline: 3.3976x; 1.3069x over previous
//
#include <hip/hip_runtime.h>
#include <hip/hip_bf16.h>

#define BATCH 16
#define INCH 16
#define HH 64
#define WW 64
#define HO 62
#define WO 62
#define LTOT (HO * WO)      // 3844
#define OUTCH 128
#define KFULL 1296
#define NTRI 45
#define NSC 8               // super-chunks, 2 channels each
#define KPC 96              // padded K per super-chunk
#define TILE_N 124          // 2 output rows per block
#define NTILES 31
#define FROW 52             // dwords per Fl row (208 B)
#define NFRAG (2 * NSC * 3 * 4 * 64)  // 12288 16B A-fragments

typedef short bf16x8 __attribute__((ext_vector_type(8)));
typedef float f32x4 __attribute__((ext_vector_type(4)));

__device__ constexpr int TRI_A[NTRI] = {
  0,0,0,0,0,0,0,0,0, 1,1,1,1,1,1,1,1, 2,2,2,2,2,2,2,
  3,3,3,3,3,3, 4,4,4,4,4, 5,5,5,5, 6,6,6, 7,7, 8};
__device__ constexpr int TRI_B[NTRI] = {
  0,1,2,3,4,5,6,7,8, 1,2,3,4,5,6,7,8, 2,3,4,5,6,7,8,
  3,4,5,6,7,8, 4,5,6,7,8, 5,6,7,8, 6,7,8, 7,8, 8};

__device__ inline unsigned short f2bf(float x) {  // RNE
  unsigned int u = __float_as_uint(x);
  unsigned int r = ((u >> 16) & 1u) + 0x7FFFu;
  return (unsigned short)((u + r) >> 16);
}
__device__ inline unsigned int pack2(float lo, float hi) {
  __hip_bfloat162 h = __float22bfloat162_rn(make_float2(lo, hi));
  return *reinterpret_cast<unsigned int*>(&h);
}

// symmetrized W element: kl in [0,96), kl = half*48 + t (t>=45 -> 0)
__device__ inline float wsym_at(const float* __restrict__ W, int sc, int o, int kl) {
  int half = kl >= 48 ? 1 : 0;
  int t = kl - 48 * half;
  if (t >= NTRI) return 0.f;
  int a = TRI_A[t], b = TRI_B[t];
  int c = sc * 2 + half;
  float v = W[o * KFULL + c * 81 + a * 9 + b];
  if (a != b) v += W[o * KFULL + c * 81 + b * 9 + a];
  return v;
}

// Prep: A-fragments in MFMA lane order.
// frag idx = (((g*NSC+sc)*3+kc)*4+mf)*64 + lane; elem e: o=g*64+mf*16+(lane&15),
// k = kc*32+(lane>>4)*8+e
__global__ void prep_wfrag(const float* __restrict__ W, unsigned short* __restrict__ Wf) {
  int idx = blockIdx.x * 256 + threadIdx.x;
  if (idx >= NFRAG) return;
  int lane = idx & 63;
  int mf = (idx >> 6) & 3;
  int rest = idx >> 8;
  int kc = rest % 3;
  int scg = rest / 3;
  int sc = scg & 7, g = scg >> 3;
  int o = g * 64 + mf * 16 + (lane & 15);
  int k0 = kc * 32 + (lane >> 4) * 8;
  unsigned short v[8];
#pragma unroll
  for (int e = 0; e < 8; ++e) v[e] = f2bf(wsym_at(W, sc, o, k0 + e));
  uint4 pk;
  pk.x = (unsigned)v[0] | ((unsigned)v[1] << 16);
  pk.y = (unsigned)v[2] | ((unsigned)v[3] << 16);
  pk.z = (unsigned)v[4] | ((unsigned)v[5] << 16);
  pk.w = (unsigned)v[6] | ((unsigned)v[7] << 16);
  *(uint4*)&Wf[(size_t)idx * 8] = pk;
}

template <bool USE_WS>
__global__ __launch_bounds__(256, 2) void conv2o_pipe(
    const float* __restrict__ X, const float* __restrict__ Wraw,
    const uint4* __restrict__ Wf, float* __restrict__ Out) {
  __shared__ float xs[INCH][4][64];            // 16 KB, staged once
  __shared__ unsigned int Fl[2][128 * FROW];   // 2 x 26 KB, double-buffered

  const int tid = threadIdx.x;
  const int blk = blockIdx.x;
  const int b = blk / NTILES;
  const int tile = blk % NTILES;
  const int y0 = tile * 2;
  const int l0 = tile * TILE_N;

  const int lane = tid & 63;
  const int wave = tid >> 6;
  const int g = wave >> 1;             // m-group (o-half)
  const int mbase = g * 64;
  const int nbase = (wave & 1) * 64;
  const int lr = lane & 15;
  const int lh = lane >> 4;

  // ---- stage all x: 1024 float4 over 256 threads ----
#pragma unroll
  for (int t = 0; t < 4; ++t) {
    int i = tid + t * 256;
    int chr = i >> 4, seg = i & 15;
    int ch = chr >> 2, r = chr & 3;
    *(float4*)&xs[ch][r][seg * 4] =
        *(const float4*)&X[((size_t)(b * INCH + ch) * HH + (y0 + r)) * WW + seg * 4];
  }

  const int q = tid & 127;
  const int half = tid >> 7;
  const int qrow = q / 62;
  const int qcol = q - qrow * 62;

  // F-compute lambda: products for (pos q, channel scn*2+half) -> Fl[buf]
  auto computeF = [&](int scn, int buf) {
    const unsigned base = q * FROW + half * 24;
    if (q < TILE_N) {
      const int ch = scn * 2 + half;
      float p[9];
#pragma unroll
      for (int di = 0; di < 3; ++di)
#pragma unroll
        for (int dj = 0; dj < 3; ++dj)
          p[di * 3 + dj] = xs[ch][qrow + di][qcol + dj];
#pragma unroll
      for (int j = 0; j < 6; ++j) {
        unsigned int d[4];
#pragma unroll
        for (int w = 0; w < 4; ++w) {
          const int m = 4 * j + w;
          float lo = (2 * m < NTRI) ? p[TRI_A[2 * m]] * p[TRI_B[2 * m]] : 0.f;
          float hi = (2 * m + 1 < NTRI) ? p[TRI_A[2 * m + 1]] * p[TRI_B[2 * m + 1]] : 0.f;
          d[w] = pack2(lo, hi);
        }
        *(uint4*)&Fl[buf][base + j * 4] = make_uint4(d[0], d[1], d[2], d[3]);
      }
    } else {
      const uint4 z = make_uint4(0u, 0u, 0u, 0u);
#pragma unroll
      for (int j = 0; j < 6; ++j) *(uint4*)&Fl[buf][base + j * 4] = z;
    }
  };

  // A-fragment load lambda (12 x uint4 for super-chunk sc)
  auto loadA = [&](uint4* ap, int sc) {
    if (USE_WS) {
      const uint4* basep = Wf + (size_t)((g * NSC + sc) * 3) * 4 * 64;
#pragma unroll
      for (int f = 0; f < 12; ++f) ap[f] = basep[f * 64 + lane];
    } else {
#pragma unroll
      for (int kc = 0; kc < 3; ++kc)
#pragma unroll
        for (int mf = 0; mf < 4; ++mf) {
          const int o = mbase + mf * 16 + lr;
          const int k0 = kc * 32 + lh * 8;
          unsigned short v[8];
#pragma unroll
          for (int e = 0; e < 8; ++e) v[e] = f2bf(wsym_at(Wraw, sc, o, k0 + e));
          uint4 pk;
          pk.x = (unsigned)v[0] | ((unsigned)v[1] << 16);
          pk.y = (unsigned)v[2] | ((unsigned)v[3] << 16);
          pk.z = (unsigned)v[4] | ((unsigned)v[5] << 16);
          pk.w = (unsigned)v[6] | ((unsigned)v[7] << 16);
          ap[kc * 4 + mf] = pk;
        }
    }
  };

  __syncthreads();  // xs ready

  uint4 apf[2][12];
  loadA(apf[0], 0);
  computeF(0, 0);

  f32x4 acc[4][4];
#pragma unroll
  for (int mf = 0; mf < 4; ++mf)
#pragma unroll
    for (int nf = 0; nf < 4; ++nf) acc[mf][nf] = (f32x4){0.f, 0.f, 0.f, 0.f};

  __syncthreads();  // F(0) ready

#pragma unroll
  for (int sc = 0; sc < NSC; ++sc) {
    const int cur = sc & 1;
    const int nxt = cur ^ 1;
    if (sc + 1 < NSC) {
      loadA(apf[nxt], sc + 1);   // lands during this iter's MFMA
      computeF(sc + 1, nxt);     // VALU, overlaps MFMA across waves
    }
#pragma unroll
    for (int kc = 0; kc < 3; ++kc) {
      const int koff = kc * 16 + lh * 4;
      bf16x8 bfr[4];
#pragma unroll
      for (int nf = 0; nf < 4; ++nf)
        bfr[nf] = *(const bf16x8*)&Fl[cur][(nbase + nf * 16 + lr) * FROW + koff];
#pragma unroll
      for (int mf = 0; mf < 4; ++mf) {
        const bf16x8 af = __builtin_bit_cast(bf16x8, apf[cur][kc * 4 + mf]);
#pragma unroll
        for (int nf = 0; nf < 4; ++nf)
          acc[mf][nf] = __builtin_amdgcn_mfma_f32_16x16x32_bf16(af, bfr[nf], acc[mf][nf], 0, 0, 0);
      }
    }
    if (sc + 1 < NSC) __syncthreads();
  }

  // ---- epilogue (layout verified in R3): D col=pos(lr), row=o(lh*4+r) ----
#pragma unroll
  for (int nf = 0; nf < 4; ++nf) {
    const int pos = nbase + nf * 16 + lr;
    if (pos < TILE_N) {
      const int l = l0 + pos;
#pragma unroll
      for (int mf = 0; mf < 4; ++mf) {
        const int o = mbase + mf * 16 + lh * 4;
        float* outp = &Out[((size_t)(b * OUTCH + o)) * LTOT + l];
#pragma unroll
        for (int r = 0; r < 4; ++r) outp[(size_t)r * LTOT] = acc[mf][nf][r];
      }
    }
  }
}

extern "C" void kernel_launch(void* const* d_in, const int* in_sizes, int n_in,
                              void* d_out, int out_size, void* d_ws, size_t ws_size,
                              hipStream_t stream) {
  const float* X = (const float*)d_in[0];
  const float* W = (const float*)d_in[1];
  float* Out = (float*)d_out;

  const size_t wf_bytes = (size_t)NFRAG * 16;  // 196608 B
  const int use_ws = (ws_size >= wf_bytes) ? 1 : 0;

  if (use_ws) {
    prep_wfrag<<<(NFRAG + 255) / 256, 256, 0, stream>>>(W, (unsigned short*)d_ws);
    conv2o_pipe<true><<<BATCH * NTILES, 256, 0, stream>>>(X, W, (const uint4*)d_ws, Out);
  } else {
    conv2o_pipe<false><<<BATCH * NTILES, 256, 0, stream>>>(X, W, (const uint4*)d_ws, Out);
  }
}